// Round 4
// baseline (94.070 us; speedup 1.0000x reference)
//
#include <hip/hip_runtime.h>
#include <hip/hip_bf16.h>
#include <stdint.h>

// QuantizedLinear: out[m][n] = (sum_k x[m][k]*W[n][k]) * scale + bias[n]
// M=256, K=4096, N=11008. W int8-valued -> exact in bf16; scale/bias in f32 epilogue.
//
// R4: BK=128 (NT=32 iters, half the barrier epochs). All issue->use gaps >= 2
// iterations in cycles (vmcnt retires IN-ORDER per wave, so a wait on a young
// load forces retirement of every older one -- R3's 1-iter A lookahead was
// serializing on the previous iter's HBM W-load):
//   W: 4-slot register ring, loaded 4 tiles (=4 iters) ahead, reg->LDS write
//      reads regs loaded 3 iters ago (~2000cy > 900cy HBM latency).
//   A: ping-pong frags, reloaded immediately after compute consumes them,
//      used 2 iters later.
// vmcnt never drained; per-iter sync = lgkmcnt(0) + s_barrier only.

#define MM 256
#define NN 11008
#define KK 4096
#define BM 128
#define BN 32
#define BK 128
#define NT (KK / BK)   // 32

typedef __bf16 bf16x8 __attribute__((ext_vector_type(8)));
typedef float  f32x4  __attribute__((ext_vector_type(4)));

// ---- pass 1: x f32 [256][4096] -> bf16 packed in MFMA-fragment order ----
// xf[(mb*128 + kb)*64 + l] = bf16x8 { x[mb*16 + (l&15)][kb*32 + (l>>4)*8 + j] }
__global__ void cvt_x_kernel(const float* __restrict__ x, bf16x8* __restrict__ xf) {
    int i  = blockIdx.x * 256 + threadIdx.x;   // 0..131071
    int l  = i & 63;
    int kb = (i >> 6) & 127;
    int mb = i >> 13;
    int m  = mb * 16 + (l & 15);
    int k  = kb * 32 + (l >> 4) * 8;
    const float* p = x + (size_t)m * KK + k;
    float4 v0 = *(const float4*)p;
    float4 v1 = *(const float4*)(p + 4);
    union { __bf16 b[8]; bf16x8 v; } t;
    t.b[0] = (__bf16)v0.x; t.b[1] = (__bf16)v0.y;
    t.b[2] = (__bf16)v0.z; t.b[3] = (__bf16)v0.w;
    t.b[4] = (__bf16)v1.x; t.b[5] = (__bf16)v1.y;
    t.b[6] = (__bf16)v1.z; t.b[7] = (__bf16)v1.w;
    xf[i] = t.v;
}

// ---- pass 2: GEMM ----
// 256 threads = 4 waves; wave w owns m-rows [mh*128 + w*32, +32) x 32 n-cols.
// LDS: B tile [32 rows][256B bf16] XOR-swizzled (byte ^= (row&7)<<4), 2 slots.
__global__ __launch_bounds__(256, 2) void qlin_gemm(
    const bf16x8* __restrict__ xf, const int* __restrict__ w,
    const float* __restrict__ scale, const float* __restrict__ bias,
    float* __restrict__ out) {

    __shared__ __align__(16) char bsm[2 * 8192];

    const int tid  = threadIdx.x;    // 0..255
    const int lane = tid & 63;
    const int wid  = tid >> 6;       // 0..3
    const int mh   = blockIdx.x;     // 0..1
    const int n0   = blockIdx.y * BN;

    // W staging: thread -> row tid>>3 (0..31), k-chunk (tid&7)*16 ints (64B)
    const int wrow = tid >> 3;
    const int wc   = tid & 7;
    const int* wbase = w + (size_t)(n0 + wrow) * KK + wc * 16;
    const int swzr = (wrow & 7) << 4;
    const int wb0 = wrow * 256 + ((wc * 32) ^ swzr);
    const int wb1 = wrow * 256 + ((wc * 32 + 16) ^ swzr);

    // B fragment read offsets [ks][fn]: row = fn*16 + (lane&15)
    int brd[4][2];
#pragma unroll
    for (int ks = 0; ks < 4; ++ks)
#pragma unroll
        for (int fn = 0; fn < 2; ++fn) {
            const int row = fn * 16 + (lane & 15);
            brd[ks][fn] = row * 256 + ((ks * 64 + (lane >> 4) * 16) ^ ((row & 7) << 4));
        }

    // A fragments: frag(fm, kb) at xf[((mh*8 + wid*2 + fm)*128 + kb)*64 + lane]
    const bf16x8* abase = xf + ((size_t)(mh * 8 + wid * 2) * 128) * 64 + lane;

    f32x4 acc[2][2] = {};

    int4 s0[4], s1[4], s2[4], s3[4];   // W(tile u) lives in slot u%4
    bf16x8 aE[4][2], aO[4][2];         // A ping-pong [ks][fm]

    auto loadW = [&](int4 (&r)[4], int t) {
        const int* p = wbase + t * BK;
        r[0] = *(const int4*)p;
        r[1] = *(const int4*)(p + 4);
        r[2] = *(const int4*)(p + 8);
        r[3] = *(const int4*)(p + 12);
    };
    auto loadA = [&](bf16x8 (&a)[4][2], int t) {
#pragma unroll
        for (int ks = 0; ks < 4; ++ks)
#pragma unroll
            for (int fm = 0; fm < 2; ++fm)
                a[ks][fm] = abase[(size_t)(fm * 128 + t * 4 + ks) * 64];
    };
    auto writeW = [&](const int4 (&r)[4], int slot) {
        union { __bf16 b[16]; bf16x8 v[2]; } c;
#pragma unroll
        for (int j = 0; j < 4; ++j) {
            c.b[j * 4 + 0] = (__bf16)(float)r[j].x;
            c.b[j * 4 + 1] = (__bf16)(float)r[j].y;
            c.b[j * 4 + 2] = (__bf16)(float)r[j].z;
            c.b[j * 4 + 3] = (__bf16)(float)r[j].w;
        }
        char* B = bsm + slot * 8192;
        *(bf16x8*)(B + wb0) = c.v[0];
        *(bf16x8*)(B + wb1) = c.v[1];
    };
    auto compute = [&](const bf16x8 (&a)[4][2], int slot) {
        const char* B = bsm + slot * 8192;
#pragma unroll
        for (int ks = 0; ks < 4; ++ks) {
            bf16x8 bf0 = *(const bf16x8*)(B + brd[ks][0]);
            bf16x8 bf1 = *(const bf16x8*)(B + brd[ks][1]);
#pragma unroll
            for (int fm = 0; fm < 2; ++fm) {
                acc[fm][0] = __builtin_amdgcn_mfma_f32_16x16x32_bf16(a[ks][fm], bf0, acc[fm][0], 0, 0, 0);
                acc[fm][1] = __builtin_amdgcn_mfma_f32_16x16x32_bf16(a[ks][fm], bf1, acc[fm][1], 0, 0, 0);
            }
        }
    };

    // ---- prologue: W(0..3) in ring, A(0),A(1) in regs, W(0) staged to LDS ----
    loadW(s0, 0);
    loadW(s1, 1);
    loadW(s2, 2);
    loadW(s3, 3);
    loadA(aE, 0);
    loadA(aO, 1);
    writeW(s0, 0);
    asm volatile("s_waitcnt lgkmcnt(0)" ::: "memory");
    __builtin_amdgcn_s_barrier();
    __builtin_amdgcn_sched_barrier(0);

    // ---- main loop: iter t = { writeW(W(t+1)); loadW(W(t+4)); compute(t);
    //                            loadA(A(t+2)); lgkm(0); barrier } ----
#define STEP(T, SW, SL, AC)                                         \
    {                                                               \
        const int t_ = (T);                                         \
        writeW(SW, (t_ + 1) & 1);                                   \
        loadW(SL, (t_ + 4 < NT) ? t_ + 4 : NT - 1);                 \
        compute(AC, t_ & 1);                                        \
        loadA(AC, (t_ + 2 < NT) ? t_ + 2 : NT - 1);                 \
        asm volatile("s_waitcnt lgkmcnt(0)" ::: "memory");          \
        __builtin_amdgcn_s_barrier();                               \
        __builtin_amdgcn_sched_barrier(0);                          \
    }

    for (int tp = 0; tp < NT / 4; ++tp) {
        const int t0 = tp * 4;
        STEP(t0 + 0, s1, s0, aE)   // write W(t+1) from s1; reload s0 <- W(t+4)
        STEP(t0 + 1, s2, s1, aO)
        STEP(t0 + 2, s3, s2, aE)
        STEP(t0 + 3, s0, s3, aO)
    }
#undef STEP

    // ---- epilogue: D layout col=lane&15, row=(lane>>4)*4+r; y = acc*scale + bias ----
    const float sc = scale[0];
    const int ecol  = lane & 15;
    const int erow0 = (lane >> 4) * 4;
#pragma unroll
    for (int fn = 0; fn < 2; ++fn) {
        const int n = n0 + fn * 16 + ecol;
        const float bv = bias[n];
#pragma unroll
        for (int fm = 0; fm < 2; ++fm) {
            const int mrow = mh * BM + wid * 32 + fm * 16 + erow0;
#pragma unroll
            for (int r = 0; r < 4; ++r)
                out[(size_t)(mrow + r) * NN + n] = acc[fm][fn][r] * sc + bv;
        }
    }
}

extern "C" void kernel_launch(void* const* d_in, const int* in_sizes, int n_in,
                              void* d_out, int out_size, void* d_ws, size_t ws_size,
                              hipStream_t stream) {
    const float* x     = (const float*)d_in[0];
    const int*   wq    = (const int*)d_in[1];
    const float* scale = (const float*)d_in[2];
    const float* bias  = (const float*)d_in[3];
    float* out = (float*)d_out;
    bf16x8* xf = (bf16x8*)d_ws;   // 2 MB packed-A scratch

    cvt_x_kernel<<<dim3(MM * KK / (256 * 8)), dim3(256), 0, stream>>>(x, xf);
    qlin_gemm<<<dim3(2, NN / BN), dim3(256), 0, stream>>>(xf, wq, scale, bias, out);
}